// Round 5
// baseline (360.514 us; speedup 1.0000x reference)
//
#include <hip/hip_runtime.h>

// CT parallel-beam pixel-driven back-projection. Static geometry.
// R18: mirror-pair structure (g <-> 180-g transpose symmetry): ws entry =
//   16 B {A_g(D,S), B_g(D,S), A_m(D,S), B_m(D,S)}; ONE ds_read_b128 gather
//   feeds 4 fdot2. 728 gathers/thread @ ~17.6 cyc (85 us) = divergent-gather
//   byte-rate floor (~58 B/cyc/CU). R19 proved conflicts are NOT the limit
//   (swizzle raised the conflict counter 5.8M->7.7M, time unchanged) ->
//   swizzle reverted. XCD batch-affinity kept (FETCH 34.6->4.4 MB).
// R20 (this round): the constant ~59 us OUTSIDE backproject (prep kernel at
//   720 small blocks + 2 serialized launches) is now the biggest term. Fuse
//   prep into the main kernel as phase 0 (188k threads, ~5 us) + a manual
//   device-scope grid barrier (512 blocks = exactly 2/CU co-resident by
//   capacity: LDS 2x50.6KB<160KB, 16 waves/CU<32; counter memset per
//   iteration via capture-legal hipMemsetAsync). Cooperative launch avoided:
//   if rejected during graph capture it would poison the capture.
// Fallbacks: ws too small for ctr -> two-kernel path; ws < arrays -> R12
// single-kernel (161 us).
#define BATCH 8
#define NVIEW 720
#define NPAIR 360
#define NGRP  180
#define NDET  736
#define IMGH  512
#define IMGW  512

#define DANG_F  ((float)(6.283185307179586 / 720.0))
#define RATIO_F ((float)(0.006641 / 0.0066))
#define UCENTER ((float)((NDET - 1) * 0.5))

#define PADDET 768        // entries per pair-iter (16 B each)
#define NITER  90         // 89 mirror pairs + 1 self-pair {0,90}
#define ITER_BYTES 12288  // 768 x 16 B
#define NBLOCKS 512
#define WS_BYTES ((size_t)BATCH * NITER * PADDET * 16)

typedef float  v2f __attribute__((ext_vector_type(2)));
typedef __fp16 v2h __attribute__((ext_vector_type(2)));
typedef __fp16 v8h __attribute__((ext_vector_type(8)));

struct alignas(16) E16 { v2h ag, bg, am, bm; };

// ---------------- prep (shared body) ----------------
// unit in [0,720): b = unit&7 (XCD affinity; 512%8==0 so fused second-unit
// keeps the block's batch), p = unit>>3. Pair p: (g,m) = p<89 ?
// (p+1, 179-p) : (0, 90). Entry j: fused (D,S) fp16 for 4 sub-arrays,
// S[j] = fwd[j]+rev[735-j], D = S[j+1]-S[j]. Overshoot taps (fwd[i+4] at
// i=732, rev[-1]) land only in entry 735's D, never read (i0 <= 731), and
// stay inside proj. Pad [736,768) unwritten, DMA'd but never read.
__device__ __forceinline__ void fuse5(const float* __restrict__ fwd,
                                      const float* __restrict__ rev,
                                      int i, float s[5]) {
    const float4 f4 = *(const float4*)(fwd + i);
    const float  f1 = fwd[i + 4];
    const float4 r4 = *(const float4*)(rev + (732 - i));  // taps i..i+3=(w,z,y,x)
    const float  r1 = rev[731 - i];                       // tap i+4
    s[0] = f4.x + r4.w; s[1] = f4.y + r4.z; s[2] = f4.z + r4.y;
    s[3] = f4.w + r4.x; s[4] = f1 + r1;
}

__device__ __forceinline__ void prep_unit(const float* __restrict__ proj,
                                          E16* __restrict__ ws,
                                          int unit, int t) {
    const int b = unit & 7;
    const int p = unit >> 3;
    const int g = (p < 89) ? p + 1   : 0;
    const int m = (p < 89) ? 179 - p : 90;
    const int i = 4 * t;
    const float* __restrict__ base = proj + (size_t)b * NVIEW * NDET;
    float sAg[5], sBg[5], sAm[5], sBm[5];
    fuse5(base + (size_t)g * NDET,         base + (size_t)(g + 360) * NDET, i, sAg);
    fuse5(base + (size_t)(g + 180) * NDET, base + (size_t)(g + 540) * NDET, i, sBg);
    fuse5(base + (size_t)m * NDET,         base + (size_t)(m + 360) * NDET, i, sAm);
    fuse5(base + (size_t)(m + 180) * NDET, base + (size_t)(m + 540) * NDET, i, sBm);
    E16* __restrict__ dst = ws + ((size_t)b * NITER + p) * PADDET + i;
#pragma unroll
    for (int k = 0; k < 4; ++k) {
        E16 e;
        e.ag = __builtin_amdgcn_cvt_pkrtz(sAg[k + 1] - sAg[k], sAg[k]);
        e.bg = __builtin_amdgcn_cvt_pkrtz(sBg[k + 1] - sBg[k], sBg[k]);
        e.am = __builtin_amdgcn_cvt_pkrtz(sAm[k + 1] - sAm[k], sAm[k]);
        e.bm = __builtin_amdgcn_cvt_pkrtz(sBm[k + 1] - sBm[k], sBm[k]);
        dst[k] = e;
    }
}

// One b128 gather -> 4 fdot2 into 4 distinct accumulators.
#define VIS(Lp, u, r0, r1, r2, r3) do {                                      \
    const float uu_ = (u);                                                   \
    const int   ii_ = (int)uu_;                                              \
    const v2h wv_ = __builtin_amdgcn_cvt_pkrtz(                              \
        __builtin_amdgcn_fractf(uu_), 1.0f);                                 \
    const v8h E_ = (Lp)[ii_];                                                \
    r0 = __builtin_amdgcn_fdot2((v2h){E_[0], E_[1]}, wv_, r0, false);        \
    r1 = __builtin_amdgcn_fdot2((v2h){E_[2], E_[3]}, wv_, r1, false);        \
    r2 = __builtin_amdgcn_fdot2((v2h){E_[4], E_[5]}, wv_, r2, false);        \
    r3 = __builtin_amdgcn_fdot2((v2h){E_[6], E_[7]}, wv_, r3, false);        \
} while (0)

// Iter-89 visit: half-pair at elems [O,O+1] -> p0 AND p1; [O+2,O+3] -> q0,q1.
#define VIS2(Lp, O, u, p0, p1, q0, q1) do {                                  \
    const float uu_ = (u);                                                   \
    const int   ii_ = (int)uu_;                                              \
    const v2h wv_ = __builtin_amdgcn_cvt_pkrtz(                              \
        __builtin_amdgcn_fractf(uu_), 1.0f);                                 \
    const v8h E_ = (Lp)[ii_];                                                \
    const v2h ha_ = {E_[(O)], E_[(O) + 1]};                                  \
    const v2h hb_ = {E_[(O) + 2], E_[(O) + 3]};                              \
    p0 = __builtin_amdgcn_fdot2(ha_, wv_, p0, false);                        \
    p1 = __builtin_amdgcn_fdot2(ha_, wv_, p1, false);                        \
    q0 = __builtin_amdgcn_fdot2(hb_, wv_, q0, false);                        \
    q1 = __builtin_amdgcn_fdot2(hb_, wv_, q1, false);                        \
} while (0)

// Iter-89 diag: one target per half.
#define VIS1(Lp, O, u, p0, q0) do {                                          \
    const float uu_ = (u);                                                   \
    const int   ii_ = (int)uu_;                                              \
    const v2h wv_ = __builtin_amdgcn_cvt_pkrtz(                              \
        __builtin_amdgcn_fractf(uu_), 1.0f);                                 \
    const v8h E_ = (Lp)[ii_];                                                \
    p0 = __builtin_amdgcn_fdot2((v2h){E_[(O)], E_[(O) + 1]}, wv_, p0, false);\
    q0 = __builtin_amdgcn_fdot2((v2h){E_[(O) + 2], E_[(O) + 3]}, wv_, q0,    \
                                false);                                      \
} while (0)

// ---------------- backproject body (shared by fused & standalone) --------
// 512 threads = 8 waves; flat block id & 7 = batch (XCD affinity), tile =
// flat>>3 -> h-tile / w-half. Phase k (k=0..43): issue(2k+2), issue(2k+3)
// -> compute iters 2k, 2k+1 -> barrier (vmcnt(0) drain waits on DMAs aged
// by two groups -> free). 4x12KB slots = double-buffered 24KB halves.
// Iter 89 = self-mirrored groups {0,90}, slot 1, after the loop.
// |g1|,|g2| <= 363.6 < 367.5 -> i0 in [3,731], +1 tap <= 732 < 736.
// R(row,col) = (511-col, row); centered R(x,y) = (-y, x).
__device__ __forceinline__ void bp_compute(
    const v8h* __restrict__ ws, float* __restrict__ out, int flat,
    v8h (*__restrict__ lds4)[PADDET], v2f* __restrict__ cs)
{
    const int tid  = threadIdx.x;
    const int wave = tid >> 6;
    const int lane = tid & 63;

    if (tid < NGRP) {
        float s, c;
        sincosf((float)tid * DANG_F, &s, &c);
        cs[tid] = (v2f){c * RATIO_F, s * RATIO_F};   // sealed by 1st barrier
    }

    const int b    = flat & 7;                           // batch -> XCD
    const int tile = flat >> 3;                          // [0, 64)
    const int h = (tile >> 1) * 8 + wave;                // [0, 256)
    const int w = (tile & 1) * 64 + lane;                // [0, 128)

    const bool dg = (w == h);                            // diagonal lane
    const bool rm = (w > h);                             // remapped lane
    const int  H  = rm ? 255 - h : h;
    const int  W  = rm ? 255 - w : w;

    const float px  = (float)W - 255.5f;
    const float py  = 255.5f - (float)H;
    // P2: normal/remap -> swap (k-addresses); diag -> base2 = (255-d,255-d).
    const float px2 = dg ? (-0.5f - (float)W) : py;
    const float py2 = dg ? ( 0.5f + (float)H) : px;

    const char* __restrict__ wsb =
        (const char*)(ws + (size_t)b * NITER * PADDET);

    float A0 = 0.f, A1 = 0.f, A2 = 0.f, A3 = 0.f;
    float B0 = 0.f, B1 = 0.f, B2 = 0.f, B3 = 0.f;
    float X0 = 0.f, X1 = 0.f, X2 = 0.f, X3 = 0.f;
    float Y0 = 0.f, Y1 = 0.f, Y2 = 0.f, Y3 = 0.f;

    auto issue = [&](int p) {
        const char* g0 = wsb + (size_t)p * ITER_BYTES;
        char* l0 = (char*)&lds4[p & 3][0];
        __builtin_amdgcn_global_load_lds(
            (const __attribute__((address_space(1))) void*)
                (g0 + wave * 1024 + lane * 16),
            (__attribute__((address_space(3))) void*)(l0 + wave * 1024),
            16, 0, 0);
        if (wave < 4) {
            const int s = 8 + wave;
            __builtin_amdgcn_global_load_lds(
                (const __attribute__((address_space(1))) void*)
                    (g0 + s * 1024 + lane * 16),
                (__attribute__((address_space(3))) void*)(l0 + s * 1024),
                16, 0, 0);
        }
    };

    const v2f cc = {UCENTER, UCENTER};
    auto groups = [&](int p) {
        const v8h* __restrict__ L = &lds4[p & 3][0];
        const v2f t  = cs[p + 1];                // group g = p+1
        const v2f m1 = {t.x, -t.y};
        const v2f m2 = {t.y, t.x};
        const v2f gA = __builtin_elementwise_fma(
            (v2f){px, px}, m1, (v2f){py, py} * m2);
        const v2f gB = __builtin_elementwise_fma(
            (v2f){px2, px2}, m1, (v2f){py2, py2} * m2);
        const v2f upA = cc + gA, umA = cc - gA;
        const v2f upB = cc + gB, umB = cc - gB;
        VIS(L, upA.x, A0, A1, X2, X3);   // C+g1
        VIS(L, umA.x, A2, A3, X0, X1);   // C-g1
        VIS(L, upA.y, A3, A0, X3, X0);   // C+g2
        VIS(L, umA.y, A1, A2, X1, X2);   // C-g2
        VIS(L, upB.x, B2, B3, Y0, Y1);   // C+g1b
        VIS(L, umB.x, B0, B1, Y2, Y3);   // C-g1b
        VIS(L, upB.y, B1, B2, Y1, Y2);   // C+g2b
        VIS(L, umB.y, B3, B0, Y3, Y0);   // C-g2b
    };

    issue(0);
    issue(1);
    __syncthreads();   // drains issues 0,1 + seals cs[]

    for (int k = 0; k < 44; ++k) {
        issue(2 * k + 2);
        issue(2 * k + 3);
        groups(2 * k);
        groups(2 * k + 1);
        __syncthreads();   // drain aged DMA (2 groups old); RW separation
    }
    groups(88);            // iter 88 (pair (89,91)), slot 0

    // -------- iter 89: self-mirrored groups {0, 90} (slot 89&3 = 1) -----
    {
        const v8h* __restrict__ L = &lds4[1][0];
        const v2f t0 = cs[0], t45 = cs[90];
        if (!dg) {
            const float g1 = px * t0.x + py * t0.y;
            const float g2 = -px * t0.y + py * t0.x;
            VIS2(L, 0, UCENTER + g1, A0, X1, A1, X2);
            VIS2(L, 0, UCENTER - g1, A2, X3, A3, X0);
            VIS2(L, 0, UCENTER + g2, A3, X2, A0, X3);
            VIS2(L, 0, UCENTER - g2, A1, X0, A2, X1);
            const float h1 = px * t45.x + py * t45.y;
            const float h2 = -px * t45.y + py * t45.x;
            VIS2(L, 4, UCENTER + h1, A0, X2, A1, X3);
            VIS2(L, 4, UCENTER - h1, A2, X0, A3, X1);
            VIS2(L, 4, UCENTER + h2, A3, X3, A0, X0);
            VIS2(L, 4, UCENTER - h2, A1, X1, A2, X2);
        } else {
            const float g1  = px * t0.x + py * t0.y;    // theta0, base1
            const float g1b = px2 * t0.x + py2 * t0.y;  // theta0, base2
            VIS2(L, 0, UCENTER + g1,  A0, A1, A1, A2);
            VIS2(L, 0, UCENTER - g1,  A2, A3, A0, A3);
            VIS2(L, 0, UCENTER + g1b, B2, B3, B3, B0);
            VIS2(L, 0, UCENTER - g1b, B0, B1, B2, B1);
            {   // theta=45, u = UCENTER
                const v2h wv_ = __builtin_amdgcn_cvt_pkrtz(0.5f, 1.0f);
                const v8h E_ = L[367];           // (int)UCENTER = 367
                const v2h ha_ = {E_[4], E_[5]};
                const v2h hb_ = {E_[6], E_[7]};
                A0 = __builtin_amdgcn_fdot2(ha_, wv_, A0, false);
                A2 = __builtin_amdgcn_fdot2(ha_, wv_, A2, false);
                B2 = __builtin_amdgcn_fdot2(ha_, wv_, B2, false);
                B0 = __builtin_amdgcn_fdot2(ha_, wv_, B0, false);
                A1 = __builtin_amdgcn_fdot2(hb_, wv_, A1, false);
                A3 = __builtin_amdgcn_fdot2(hb_, wv_, A3, false);
                B3 = __builtin_amdgcn_fdot2(hb_, wv_, B3, false);
                B1 = __builtin_amdgcn_fdot2(hb_, wv_, B1, false);
            }
            const float e1 = (px + px) * t45.x;
            const float e2 = (px2 + px2) * t45.x;
            VIS1(L, 4, UCENTER + e1, A1, A2);
            VIS1(L, 4, UCENTER - e1, A3, A0);
            VIS1(L, 4, UCENTER + e2, B3, B0);
            VIS1(L, 4, UCENTER - e2, B1, B2);
        }
    }

    // -------- write: 8 pixels, two R-orbits --------
    const float aE0 = dg ? X0 : Y0, aE1 = dg ? X1 : Y1;
    const float aE2 = dg ? X2 : Y2, aE3 = dg ? X3 : Y3;
    const float bE0 = dg ? Y0 : X0, bE1 = dg ? Y1 : X1;
    const float bE2 = dg ? Y2 : X2, bE3 = dg ? Y3 : X3;
    const float a0 = (A0 + aE0) * DANG_F, a1 = (A1 + aE1) * DANG_F;
    const float a2 = (A2 + aE2) * DANG_F, a3 = (A3 + aE3) * DANG_F;
    const float b0 = (B0 + bE0) * DANG_F, b1 = (B1 + bE1) * DANG_F;
    const float b2 = (B2 + bE2) * DANG_F, b3 = (B3 + bE3) * DANG_F;

    float* __restrict__ o = out + (size_t)b * IMGH * IMGW;
    const int Qr = dg ? 256 + H : W;
    const int Qc = dg ? 256 + W : H;
    o[H * IMGW + W]                         = a0;
    o[(511 - W) * IMGW + H]                 = a1;
    o[(511 - H) * IMGW + (511 - W)]         = a2;
    o[W * IMGW + (511 - H)]                 = a3;
    o[Qr * IMGW + Qc]                       = b0;
    o[(511 - Qc) * IMGW + Qr]               = b1;
    o[(511 - Qr) * IMGW + (511 - Qc)]       = b2;
    o[Qc * IMGW + (511 - Qr)]               = b3;
}

// ---------------- fused kernel (R20) ----------------
// Phase 0: prep. Block `flat` preps unit `flat` (threads 0-183) and unit
// `flat+512` (threads 184-367, only blocks flat<208): covers all 720 units
// once; unit&7 == flat&7 (512%8==0) keeps batch->XCD affinity. Phase gate:
// device-scope arrive-and-spin barrier on *ctr (memset to 0 per iteration
// by the launcher). Co-residency by capacity: 512 blocks = exactly 2/CU
// (LDS 2x50.6KB < 160KB, 16 waves/CU < 32) -> no deadlock. Phase 1: bp.
__global__ __launch_bounds__(512, 4) void fused_kernel(
    const float* __restrict__ proj, E16* __restrict__ ws,
    float* __restrict__ out, unsigned int* __restrict__ ctr)
{
    __shared__ alignas(16) v8h lds4[4][PADDET];  // 4 x 12288 B ring
    __shared__ v2f cs[NGRP];

    const int tid  = threadIdx.x;
    const int flat = ((int)blockIdx.z * 32 + (int)blockIdx.y) * 2
                     + (int)blockIdx.x;

    if (tid < 368) {
        const int second = (tid >= 184);
        const int unit = flat + (second ? NBLOCKS : 0);
        if (unit < 720)
            prep_unit(proj, ws, unit, tid - 184 * second);
    }

    // -------- grid barrier: release prep writes, arrive, spin --------
    __threadfence();
    __syncthreads();
    if (tid == 0) {
        __hip_atomic_fetch_add(ctr, 1u, __ATOMIC_ACQ_REL,
                               __HIP_MEMORY_SCOPE_AGENT);
        while (__hip_atomic_load(ctr, __ATOMIC_ACQUIRE,
                                 __HIP_MEMORY_SCOPE_AGENT) < NBLOCKS)
            __builtin_amdgcn_s_sleep(8);
    }
    __syncthreads();
    __threadfence();

    bp_compute((const v8h*)ws, out, flat, lds4, cs);
}

// ---------------- standalone pair (fallback if ctr doesn't fit) ---------
__global__ __launch_bounds__(192) void prep_kernel(
    const float* __restrict__ proj, E16* __restrict__ ws)
{
    const int t = threadIdx.x;
    if (t >= 184) return;
    const int flat = (int)blockIdx.y * 90 + (int)blockIdx.x;
    prep_unit(proj, ws, flat, t);
}

__global__ __launch_bounds__(512, 4) void backproject_dma_kernel(
    const v8h* __restrict__ ws, float* __restrict__ out)
{
    __shared__ alignas(16) v8h lds4[4][PADDET];
    __shared__ v2f cs[NGRP];
    const int flat = ((int)blockIdx.z * 32 + (int)blockIdx.y) * 2
                     + (int)blockIdx.x;
    bp_compute(ws, out, flat, lds4, cs);
}

// ---------------- fallback (R12, proven 161 us) ----------------
struct Stage { float4 f4, r4; float f1, r1; };

__device__ __forceinline__ void fb_load(const float* __restrict__ sino,
                                        int k, int t, Stage& S) {
    if (t < 368) {
        const int p  = (t >= 184);
        const int i  = 4 * (t - 184 * p);
        const int vf = k + 180 * p;
        const float* __restrict__ fwd = sino + vf * NDET;
        const float* __restrict__ rev = sino + (vf + NPAIR) * NDET;
        S.f4 = *(const float4*)(fwd + i);
        S.f1 = fwd[i + 4];
        S.r4 = *(const float4*)(rev + (732 - i));
        S.r1 = rev[731 - i];
    }
}

__device__ __forceinline__ void fb_write(v2h* __restrict__ L, int t,
                                         const Stage& S) {
    if (t < 368) {
        const int p = (t >= 184);
        const int i = 4 * (t - 184 * p);
        const float s0 = S.f4.x + S.r4.w;
        const float s1 = S.f4.y + S.r4.z;
        const float s2 = S.f4.z + S.r4.y;
        const float s3 = S.f4.w + S.r4.x;
        const float s4 = S.f1 + S.r1;
        const v2h n0 = __builtin_amdgcn_cvt_pkrtz(s1 - s0, s0);
        const v2h n1 = __builtin_amdgcn_cvt_pkrtz(s2 - s1, s1);
        const v2h n2 = __builtin_amdgcn_cvt_pkrtz(s3 - s2, s2);
        const v2h n3 = __builtin_amdgcn_cvt_pkrtz(s4 - s3, s3);
        struct alignas(16) H4 { v2h a, b, c, d; };
        *(H4*)(L + p * NDET + i) = H4{n0, n1, n2, n3};
    }
}

__device__ __forceinline__ void fb_visit(const v2h* __restrict__ L,
                                         float u, float& accA, float& accB) {
    const int   i0 = (int)u;
    const float fr = __builtin_amdgcn_fractf(u);
    const v2h wv = __builtin_amdgcn_cvt_pkrtz(fr, 1.0f);
    const v2h A = L[i0];
    const v2h B = L[i0 + NDET];
    accA = __builtin_amdgcn_fdot2(A, wv, accA, false);
    accB = __builtin_amdgcn_fdot2(B, wv, accB, false);
}

__global__ __launch_bounds__(512, 4) void backproject_fb_kernel(
    const float* __restrict__ proj, float* __restrict__ out)
{
    __shared__ alignas(16) v2h lds[2][2][2 * NDET];
    __shared__ v2f cs[NGRP];

    const int tid = threadIdx.x;
    if (tid < NGRP) {
        float s, c;
        sincosf((float)tid * DANG_F, &s, &c);
        cs[tid] = (v2f){c * RATIO_F, s * RATIO_F};
    }

    const int b    = blockIdx.z;
    const int lane = tid & 63;
    const int h    = (int)blockIdx.y * 8 + (tid >> 6);
    const int w0   = (int)blockIdx.x * 64 + lane;

    const float px = (float)w0 - (float)(IMGW - 1) * 0.5f;
    const float py = (float)(IMGH - 1) * 0.5f - (float)h;

    const float* __restrict__ sino = proj + (size_t)b * NVIEW * NDET;

    float a0 = 0.f, a1 = 0.f, a2 = 0.f, a3 = 0.f;
    float b0 = 0.f, b1 = 0.f, b2 = 0.f, b3 = 0.f;

    Stage s0 = {}, s1 = {};
    fb_load(sino, 0, tid, s0);
    fb_load(sino, 1, tid, s1);
    fb_write(lds[0][0], tid, s0);
    fb_write(lds[0][1], tid, s1);
    fb_load(sino, 2, tid, s0);
    fb_load(sino, 3, tid, s1);
    __syncthreads();

    for (int gg = 0; gg < NGRP; gg += 2) {
        const int buf = (gg >> 1) & 1;
#pragma unroll
        for (int sub = 0; sub < 2; ++sub) {
            const v2h* __restrict__ L = lds[buf][sub];
            const v2f t = cs[gg + sub];
            const v2f m1 = {t.x, -t.y};
            const v2f m2 = {t.y, t.x};
            const v2f pxv = {px, px};
            const v2f pyv = {py, py};
            const v2f gvec = __builtin_elementwise_fma(pxv, m1, pyv * m2);
            const v2f cc = {UCENTER, UCENTER};
            const v2f up = cc + gvec;
            const v2f um = cc - gvec;
            const v2f dd = {128.0f, 128.0f};
            const v2f dm = dd * m1;
            const v2f vp = up + dm;
            const v2f vm = um - dm;

            fb_visit(L, up.x, a0, a1);
            fb_visit(L, um.x, a2, a3);
            fb_visit(L, up.y, a3, a0);
            fb_visit(L, um.y, a1, a2);
            fb_visit(L, vp.x, b0, b1);
            fb_visit(L, vm.x, b2, b3);
            fb_visit(L, vp.y, b3, b0);
            fb_visit(L, vm.y, b1, b2);
        }
        if (gg < NGRP - 2) {
            fb_write(lds[buf ^ 1][0], tid, s0);
            fb_write(lds[buf ^ 1][1], tid, s1);
            if (gg < NGRP - 4) {
                fb_load(sino, gg + 4, tid, s0);
                fb_load(sino, gg + 5, tid, s1);
            }
            __syncthreads();
        }
    }

    float* __restrict__ o = out + (size_t)b * IMGH * IMGW;
    const int hm  = (IMGH - 1) - h;
    const int w1  = w0 + 128;
    const int wm0 = (IMGW - 1) - w0;
    const int wm1 = (IMGW - 1) - w1;
    o[h   * IMGW + w0 ] = a0 * DANG_F;
    o[wm0 * IMGW + h  ] = a1 * DANG_F;
    o[hm  * IMGW + wm0] = a2 * DANG_F;
    o[w0  * IMGW + hm ] = a3 * DANG_F;
    o[h   * IMGW + w1 ] = b0 * DANG_F;
    o[wm1 * IMGW + h  ] = b1 * DANG_F;
    o[hm  * IMGW + wm1] = b2 * DANG_F;
    o[w1  * IMGW + hm ] = b3 * DANG_F;
}

extern "C" void kernel_launch(void* const* d_in, const int* in_sizes, int n_in,
                              void* d_out, int out_size, void* d_ws, size_t ws_size,
                              hipStream_t stream) {
    const float* proj = (const float*)d_in[0];
    float* out = (float*)d_out;

    if (ws_size >= WS_BYTES + 64) {
        E16* ws = (E16*)d_ws;
        unsigned int* ctr = (unsigned int*)((char*)d_ws + WS_BYTES);
        hipMemsetAsync(ctr, 0, sizeof(unsigned int), stream);
        fused_kernel<<<dim3(2, 32, BATCH), 512, 0, stream>>>(proj, ws, out, ctr);
    } else if (ws_size >= WS_BYTES) {
        E16* ws = (E16*)d_ws;
        prep_kernel<<<dim3(90, BATCH), 192, 0, stream>>>(proj, ws);
        backproject_dma_kernel<<<dim3(2, 32, BATCH), 512, 0, stream>>>(
            (const v8h*)ws, out);
    } else {
        backproject_fb_kernel<<<dim3(2, 32, BATCH), 512, 0, stream>>>(proj, out);
    }
}

// Round 6
// 138.698 us; speedup vs baseline: 2.5993x; 2.5993x over previous
//
#include <hip/hip_runtime.h>

// CT parallel-beam pixel-driven back-projection. Static geometry.
// Structure (R18/R19, measured-best):
//   prep_kernel: builds ws entry = 16 B {A_g(D,S), B_g(D,S), A_m(D,S),
//     B_m(D,S)} per detector bin for mirror pair (g, m=180-g); S[i] =
//     fwd[i]+rev[735-i], D = S[i+1]-S[i], fp16. R21: tail taps fwd[i+4] /
//     rev[731-i] come from __shfl_down(f4.x/r4.w, 1) instead of 8 scalar
//     stride-16B loads (each cost a full dwordx4's cache lines for 1/4 the
//     data); wave-boundary lanes (t&63)==63 take a guarded real load.
//     The t=183<-184 handoff is correct (t=184 loads i=736's data = exactly
//     the overshoot taps, which are in-bounds and only feed entry 735's D,
//     never read since i0 <= 731).
//   backproject_dma_kernel: ONE ds_read_b128 gather feeds 4 fdot2 (group g
//     for own rotation orbit + group m for transposed orbit). 728 gathers/
//     thread @ ~17.6 cyc = LDS divergent-gather byte-rate floor (~58 B/cyc;
//     R16: b32=6.0cyc, b64=12.3cyc, b128=17.6cyc — same B/cyc; R19 proved
//     bank conflicts NOT the limit: swizzle moved the counter 5.8M->7.7M
//     with zero time change; R17 proved vm-pipe gather 40cyc = worse).
//     XCD batch-affinity (flat&7 = batch): FETCH 34.6->4.4 MB. 45 barriers
//     (2 pair-iters per phase, 4x12KB ring = double-buffered 24KB halves).
//   R20 fused+grid-barrier experiment: 320us (barrier machinery ~235us
//     stall) -> reverted. It measured the fixed harness overhead: ~40us.
// Fallback: if ws_size < needed, launch the proven R12 kernel (161 us).
#define BATCH 8
#define NVIEW 720
#define NPAIR 360
#define NGRP  180
#define NDET  736
#define IMGH  512
#define IMGW  512

#define DANG_F  ((float)(6.283185307179586 / 720.0))
#define RATIO_F ((float)(0.006641 / 0.0066))
#define UCENTER ((float)((NDET - 1) * 0.5))

#define PADDET 768        // entries per pair-iter (16 B each)
#define NITER  90         // 89 mirror pairs + 1 self-pair {0,90}
#define ITER_BYTES 12288  // 768 x 16 B
#define WS_BYTES ((size_t)BATCH * NITER * PADDET * 16)

typedef float  v2f __attribute__((ext_vector_type(2)));
typedef __fp16 v2h __attribute__((ext_vector_type(2)));
typedef __fp16 v8h __attribute__((ext_vector_type(8)));

struct alignas(16) E16 { v2h ag, bg, am, bm; };

// ---------------- prep kernel (R21: shuffle tail-taps) ----------------
// grid (90, 8) = 720 blocks; flat = y*90+x; batch = flat&7 (XCD affinity:
// consecutive dispatch round-robins XCDs, so flat&7 pins each batch's
// blocks to one XCD, matching the bp kernel's mapping), pair p = flat>>3.
// Pair p: (g,m) = p<89 ? (p+1, 179-p) : (0, 90). Block 192, ALL threads
// execute loads+shfl (shfl needs active lanes); only t<184 stores.
// Threads 184..191 load i=736..764 data: in-bounds (rows stay within the
// batch's [0,720) range +-1 row, entries +-32).
__global__ __launch_bounds__(192) void prep_kernel(
    const float* __restrict__ proj, E16* __restrict__ ws)
{
    const int t = threadIdx.x;
    const int flat = (int)blockIdx.y * 90 + (int)blockIdx.x;
    const int b = flat & 7;
    const int p = flat >> 3;
    const int g = (p < 89) ? p + 1   : 0;
    const int m = (p < 89) ? 179 - p : 90;
    const int i = 4 * t;
    const float* __restrict__ base = proj + (size_t)b * NVIEW * NDET;
    const float* __restrict__ fA = base + (size_t)g * NDET;
    const float* __restrict__ rA = fA + (size_t)NPAIR * NDET;   // g+360
    const float* __restrict__ fB = fA + (size_t)NGRP * NDET;    // g+180
    const float* __restrict__ rB = fB + (size_t)NPAIR * NDET;   // g+540
    const float* __restrict__ fM = base + (size_t)m * NDET;
    const float* __restrict__ rM = fM + (size_t)NPAIR * NDET;   // m+360
    const float* __restrict__ fN = fM + (size_t)NGRP * NDET;    // m+180
    const float* __restrict__ rN = fN + (size_t)NPAIR * NDET;   // m+540

    const float4 fa = *(const float4*)(fA + i);
    const float4 ra = *(const float4*)(rA + (732 - i));  // taps i..i+3=(w,z,y,x)
    const float4 fb = *(const float4*)(fB + i);
    const float4 rb = *(const float4*)(rB + (732 - i));
    const float4 fm = *(const float4*)(fM + i);
    const float4 rm = *(const float4*)(rM + (732 - i));
    const float4 fn = *(const float4*)(fN + i);
    const float4 rn = *(const float4*)(rN + (732 - i));

    // Tail taps: thread t needs fwd[i+4] = thread(t+1).f4.x and
    // rev[731-i] = thread(t+1).r4.w. Wave-boundary lanes load for real.
    float fa1 = __shfl_down(fa.x, 1), ra1 = __shfl_down(ra.w, 1);
    float fb1 = __shfl_down(fb.x, 1), rb1 = __shfl_down(rb.w, 1);
    float fm1 = __shfl_down(fm.x, 1), rm1 = __shfl_down(rm.w, 1);
    float fn1 = __shfl_down(fn.x, 1), rn1 = __shfl_down(rn.w, 1);
    if ((t & 63) == 63) {
        fa1 = fA[i + 4]; ra1 = rA[731 - i];
        fb1 = fB[i + 4]; rb1 = rB[731 - i];
        fm1 = fM[i + 4]; rm1 = rM[731 - i];
        fn1 = fN[i + 4]; rn1 = rN[731 - i];
    }

    if (t >= 184) return;

    const float sA[5] = {fa.x + ra.w, fa.y + ra.z, fa.z + ra.y,
                         fa.w + ra.x, fa1 + ra1};
    const float sB[5] = {fb.x + rb.w, fb.y + rb.z, fb.z + rb.y,
                         fb.w + rb.x, fb1 + rb1};
    const float sM[5] = {fm.x + rm.w, fm.y + rm.z, fm.z + rm.y,
                         fm.w + rm.x, fm1 + rm1};
    const float sN[5] = {fn.x + rn.w, fn.y + rn.z, fn.z + rn.y,
                         fn.w + rn.x, fn1 + rn1};

    E16* __restrict__ dst = ws + ((size_t)b * NITER + p) * PADDET + i;
#pragma unroll
    for (int k = 0; k < 4; ++k) {
        E16 e;
        e.ag = __builtin_amdgcn_cvt_pkrtz(sA[k + 1] - sA[k], sA[k]);
        e.bg = __builtin_amdgcn_cvt_pkrtz(sB[k + 1] - sB[k], sB[k]);
        e.am = __builtin_amdgcn_cvt_pkrtz(sM[k + 1] - sM[k], sM[k]);
        e.bm = __builtin_amdgcn_cvt_pkrtz(sN[k + 1] - sN[k], sN[k]);
        dst[k] = e;
    }
}

// One b128 gather -> 4 fdot2 into 4 distinct accumulators.
#define VIS(Lp, u, r0, r1, r2, r3) do {                                      \
    const float uu_ = (u);                                                   \
    const int   ii_ = (int)uu_;                                              \
    const v2h wv_ = __builtin_amdgcn_cvt_pkrtz(                              \
        __builtin_amdgcn_fractf(uu_), 1.0f);                                 \
    const v8h E_ = (Lp)[ii_];                                                \
    r0 = __builtin_amdgcn_fdot2((v2h){E_[0], E_[1]}, wv_, r0, false);        \
    r1 = __builtin_amdgcn_fdot2((v2h){E_[2], E_[3]}, wv_, r1, false);        \
    r2 = __builtin_amdgcn_fdot2((v2h){E_[4], E_[5]}, wv_, r2, false);        \
    r3 = __builtin_amdgcn_fdot2((v2h){E_[6], E_[7]}, wv_, r3, false);        \
} while (0)

// Iter-89 visit: half-pair at elems [O,O+1] -> p0 AND p1; [O+2,O+3] -> q0,q1.
#define VIS2(Lp, O, u, p0, p1, q0, q1) do {                                  \
    const float uu_ = (u);                                                   \
    const int   ii_ = (int)uu_;                                              \
    const v2h wv_ = __builtin_amdgcn_cvt_pkrtz(                              \
        __builtin_amdgcn_fractf(uu_), 1.0f);                                 \
    const v8h E_ = (Lp)[ii_];                                                \
    const v2h ha_ = {E_[(O)], E_[(O) + 1]};                                  \
    const v2h hb_ = {E_[(O) + 2], E_[(O) + 3]};                              \
    p0 = __builtin_amdgcn_fdot2(ha_, wv_, p0, false);                        \
    p1 = __builtin_amdgcn_fdot2(ha_, wv_, p1, false);                        \
    q0 = __builtin_amdgcn_fdot2(hb_, wv_, q0, false);                        \
    q1 = __builtin_amdgcn_fdot2(hb_, wv_, q1, false);                        \
} while (0)

// Iter-89 diag: one target per half.
#define VIS1(Lp, O, u, p0, q0) do {                                          \
    const float uu_ = (u);                                                   \
    const int   ii_ = (int)uu_;                                              \
    const v2h wv_ = __builtin_amdgcn_cvt_pkrtz(                              \
        __builtin_amdgcn_fractf(uu_), 1.0f);                                 \
    const v8h E_ = (Lp)[ii_];                                                \
    p0 = __builtin_amdgcn_fdot2((v2h){E_[(O)], E_[(O) + 1]}, wv_, p0, false);\
    q0 = __builtin_amdgcn_fdot2((v2h){E_[(O) + 2], E_[(O) + 3]}, wv_, q0,    \
                                false);                                      \
} while (0)

// ---------------- main kernel (DMA path) ----------------
// 512 threads = 8 waves; flat block id & 7 = batch (XCD affinity), tile =
// flat>>3 -> h-tile / w-half. Phase k (k=0..43): issue(2k+2), issue(2k+3)
// -> compute iters 2k, 2k+1 -> barrier (vmcnt(0) drain waits on DMAs aged
// by two groups -> free). 4x12KB slots = double-buffered 24KB halves.
// Iter 89 = self-mirrored groups {0,90}, slot 1, after the loop.
// Thread basing: fundamental domain of dihedral-8; lane (h,w), h in
// [0,256), w in [0,128): w<h -> P1=(h,w); w>h -> P1=(255-h,255-w); w==h ->
// diagonal, P1=(d,d) plus second base (255-d,255-d). Accumulator banks
// A/X/B/Y; inner loop lane-uniform, normal-vs-diag differs only in coords
// and a write-time X/Y select.
// |g1|,|g2| <= 363.6 < 367.5 -> i0 in [3,731], +1 tap <= 732 < 736.
// R(row,col) = (511-col, row); centered R(x,y) = (-y, x).
__global__ __launch_bounds__(512, 4) void backproject_dma_kernel(
    const v8h* __restrict__ ws, float* __restrict__ out)
{
    __shared__ alignas(16) v8h lds4[4][PADDET];  // 4 x 12288 B ring
    __shared__ v2f cs[NGRP];

    const int tid  = threadIdx.x;
    const int wave = tid >> 6;
    const int lane = tid & 63;

    if (tid < NGRP) {
        float s, c;
        sincosf((float)tid * DANG_F, &s, &c);
        cs[tid] = (v2f){c * RATIO_F, s * RATIO_F};   // sealed by 1st barrier
    }

    const int flat = ((int)blockIdx.z * 32 + (int)blockIdx.y) * 2
                     + (int)blockIdx.x;
    const int b    = flat & 7;                           // batch -> XCD
    const int tile = flat >> 3;                          // [0, 64)
    const int h = (tile >> 1) * 8 + wave;                // [0, 256)
    const int w = (tile & 1) * 64 + lane;                // [0, 128)

    const bool dg = (w == h);                            // diagonal lane
    const bool rm = (w > h);                             // remapped lane
    const int  H  = rm ? 255 - h : h;
    const int  W  = rm ? 255 - w : w;

    const float px  = (float)W - 255.5f;
    const float py  = 255.5f - (float)H;
    // P2: normal/remap -> swap (k-addresses); diag -> base2 = (255-d,255-d).
    const float px2 = dg ? (-0.5f - (float)W) : py;
    const float py2 = dg ? ( 0.5f + (float)H) : px;

    const char* __restrict__ wsb =
        (const char*)(ws + (size_t)b * NITER * PADDET);

    float A0 = 0.f, A1 = 0.f, A2 = 0.f, A3 = 0.f;
    float B0 = 0.f, B1 = 0.f, B2 = 0.f, B3 = 0.f;
    float X0 = 0.f, X1 = 0.f, X2 = 0.f, X3 = 0.f;
    float Y0 = 0.f, Y1 = 0.f, Y2 = 0.f, Y3 = 0.f;

    auto issue = [&](int p) {
        const char* g0 = wsb + (size_t)p * ITER_BYTES;
        char* l0 = (char*)&lds4[p & 3][0];
        __builtin_amdgcn_global_load_lds(
            (const __attribute__((address_space(1))) void*)
                (g0 + wave * 1024 + lane * 16),
            (__attribute__((address_space(3))) void*)(l0 + wave * 1024),
            16, 0, 0);
        if (wave < 4) {
            const int s = 8 + wave;
            __builtin_amdgcn_global_load_lds(
                (const __attribute__((address_space(1))) void*)
                    (g0 + s * 1024 + lane * 16),
                (__attribute__((address_space(3))) void*)(l0 + s * 1024),
                16, 0, 0);
        }
    };

    const v2f cc = {UCENTER, UCENTER};
    auto groups = [&](int p) {
        const v8h* __restrict__ L = &lds4[p & 3][0];
        const v2f t  = cs[p + 1];                // group g = p+1
        const v2f m1 = {t.x, -t.y};
        const v2f m2 = {t.y, t.x};
        const v2f gA = __builtin_elementwise_fma(
            (v2f){px, px}, m1, (v2f){py, py} * m2);
        const v2f gB = __builtin_elementwise_fma(
            (v2f){px2, px2}, m1, (v2f){py2, py2} * m2);
        const v2f upA = cc + gA, umA = cc - gA;
        const v2f upB = cc + gB, umB = cc - gB;
        VIS(L, upA.x, A0, A1, X2, X3);   // C+g1
        VIS(L, umA.x, A2, A3, X0, X1);   // C-g1
        VIS(L, upA.y, A3, A0, X3, X0);   // C+g2
        VIS(L, umA.y, A1, A2, X1, X2);   // C-g2
        VIS(L, upB.x, B2, B3, Y0, Y1);   // C+g1b
        VIS(L, umB.x, B0, B1, Y2, Y3);   // C-g1b
        VIS(L, upB.y, B1, B2, Y1, Y2);   // C+g2b
        VIS(L, umB.y, B3, B0, Y3, Y0);   // C-g2b
    };

    issue(0);
    issue(1);
    __syncthreads();   // drains issues 0,1 + seals cs[]

    for (int k = 0; k < 44; ++k) {
        issue(2 * k + 2);
        issue(2 * k + 3);
        groups(2 * k);
        groups(2 * k + 1);
        __syncthreads();   // drain aged DMA (2 groups old); RW separation
    }
    groups(88);            // iter 88 (pair (89,91)), slot 0

    // -------- iter 89: self-mirrored groups {0, 90} (slot 89&3 = 1) -----
    {
        const v8h* __restrict__ L = &lds4[1][0];
        const v2f t0 = cs[0], t45 = cs[90];
        if (!dg) {
            const float g1 = px * t0.x + py * t0.y;
            const float g2 = -px * t0.y + py * t0.x;
            VIS2(L, 0, UCENTER + g1, A0, X1, A1, X2);
            VIS2(L, 0, UCENTER - g1, A2, X3, A3, X0);
            VIS2(L, 0, UCENTER + g2, A3, X2, A0, X3);
            VIS2(L, 0, UCENTER - g2, A1, X0, A2, X1);
            const float h1 = px * t45.x + py * t45.y;
            const float h2 = -px * t45.y + py * t45.x;
            VIS2(L, 4, UCENTER + h1, A0, X2, A1, X3);
            VIS2(L, 4, UCENTER - h1, A2, X0, A3, X1);
            VIS2(L, 4, UCENTER + h2, A3, X3, A0, X0);
            VIS2(L, 4, UCENTER - h2, A1, X1, A2, X2);
        } else {
            const float g1  = px * t0.x + py * t0.y;    // theta0, base1
            const float g1b = px2 * t0.x + py2 * t0.y;  // theta0, base2
            VIS2(L, 0, UCENTER + g1,  A0, A1, A1, A2);
            VIS2(L, 0, UCENTER - g1,  A2, A3, A0, A3);
            VIS2(L, 0, UCENTER + g1b, B2, B3, B3, B0);
            VIS2(L, 0, UCENTER - g1b, B0, B1, B2, B1);
            {   // theta=45, u = UCENTER
                const v2h wv_ = __builtin_amdgcn_cvt_pkrtz(0.5f, 1.0f);
                const v8h E_ = L[367];           // (int)UCENTER = 367
                const v2h ha_ = {E_[4], E_[5]};
                const v2h hb_ = {E_[6], E_[7]};
                A0 = __builtin_amdgcn_fdot2(ha_, wv_, A0, false);
                A2 = __builtin_amdgcn_fdot2(ha_, wv_, A2, false);
                B2 = __builtin_amdgcn_fdot2(ha_, wv_, B2, false);
                B0 = __builtin_amdgcn_fdot2(ha_, wv_, B0, false);
                A1 = __builtin_amdgcn_fdot2(hb_, wv_, A1, false);
                A3 = __builtin_amdgcn_fdot2(hb_, wv_, A3, false);
                B3 = __builtin_amdgcn_fdot2(hb_, wv_, B3, false);
                B1 = __builtin_amdgcn_fdot2(hb_, wv_, B1, false);
            }
            const float e1 = (px + px) * t45.x;
            const float e2 = (px2 + px2) * t45.x;
            VIS1(L, 4, UCENTER + e1, A1, A2);
            VIS1(L, 4, UCENTER - e1, A3, A0);
            VIS1(L, 4, UCENTER + e2, B3, B0);
            VIS1(L, 4, UCENTER - e2, B1, B2);
        }
    }

    // -------- write: 8 pixels, two R-orbits --------
    const float aE0 = dg ? X0 : Y0, aE1 = dg ? X1 : Y1;
    const float aE2 = dg ? X2 : Y2, aE3 = dg ? X3 : Y3;
    const float bE0 = dg ? Y0 : X0, bE1 = dg ? Y1 : X1;
    const float bE2 = dg ? Y2 : X2, bE3 = dg ? Y3 : X3;
    const float a0 = (A0 + aE0) * DANG_F, a1 = (A1 + aE1) * DANG_F;
    const float a2 = (A2 + aE2) * DANG_F, a3 = (A3 + aE3) * DANG_F;
    const float b0 = (B0 + bE0) * DANG_F, b1 = (B1 + bE1) * DANG_F;
    const float b2 = (B2 + bE2) * DANG_F, b3 = (B3 + bE3) * DANG_F;

    float* __restrict__ o = out + (size_t)b * IMGH * IMGW;
    const int Qr = dg ? 256 + H : W;
    const int Qc = dg ? 256 + W : H;
    o[H * IMGW + W]                         = a0;
    o[(511 - W) * IMGW + H]                 = a1;
    o[(511 - H) * IMGW + (511 - W)]         = a2;
    o[W * IMGW + (511 - H)]                 = a3;
    o[Qr * IMGW + Qc]                       = b0;
    o[(511 - Qc) * IMGW + Qr]               = b1;
    o[(511 - Qr) * IMGW + (511 - Qc)]       = b2;
    o[Qc * IMGW + (511 - Qr)]               = b3;
}

// ---------------- fallback (R12, proven 161 us) ----------------
struct Stage { float4 f4, r4; float f1, r1; };

__device__ __forceinline__ void fb_load(const float* __restrict__ sino,
                                        int k, int t, Stage& S) {
    if (t < 368) {
        const int p  = (t >= 184);
        const int i  = 4 * (t - 184 * p);
        const int vf = k + 180 * p;
        const float* __restrict__ fwd = sino + vf * NDET;
        const float* __restrict__ rev = sino + (vf + NPAIR) * NDET;
        S.f4 = *(const float4*)(fwd + i);
        S.f1 = fwd[i + 4];
        S.r4 = *(const float4*)(rev + (732 - i));
        S.r1 = rev[731 - i];
    }
}

__device__ __forceinline__ void fb_write(v2h* __restrict__ L, int t,
                                         const Stage& S) {
    if (t < 368) {
        const int p = (t >= 184);
        const int i = 4 * (t - 184 * p);
        const float s0 = S.f4.x + S.r4.w;
        const float s1 = S.f4.y + S.r4.z;
        const float s2 = S.f4.z + S.r4.y;
        const float s3 = S.f4.w + S.r4.x;
        const float s4 = S.f1 + S.r1;
        const v2h n0 = __builtin_amdgcn_cvt_pkrtz(s1 - s0, s0);
        const v2h n1 = __builtin_amdgcn_cvt_pkrtz(s2 - s1, s1);
        const v2h n2 = __builtin_amdgcn_cvt_pkrtz(s3 - s2, s2);
        const v2h n3 = __builtin_amdgcn_cvt_pkrtz(s4 - s3, s3);
        struct alignas(16) H4 { v2h a, b, c, d; };
        *(H4*)(L + p * NDET + i) = H4{n0, n1, n2, n3};
    }
}

__device__ __forceinline__ void fb_visit(const v2h* __restrict__ L,
                                         float u, float& accA, float& accB) {
    const int   i0 = (int)u;
    const float fr = __builtin_amdgcn_fractf(u);
    const v2h wv = __builtin_amdgcn_cvt_pkrtz(fr, 1.0f);
    const v2h A = L[i0];
    const v2h B = L[i0 + NDET];
    accA = __builtin_amdgcn_fdot2(A, wv, accA, false);
    accB = __builtin_amdgcn_fdot2(B, wv, accB, false);
}

__global__ __launch_bounds__(512, 4) void backproject_fb_kernel(
    const float* __restrict__ proj, float* __restrict__ out)
{
    __shared__ alignas(16) v2h lds[2][2][2 * NDET];
    __shared__ v2f cs[NGRP];

    const int tid = threadIdx.x;
    if (tid < NGRP) {
        float s, c;
        sincosf((float)tid * DANG_F, &s, &c);
        cs[tid] = (v2f){c * RATIO_F, s * RATIO_F};
    }

    const int b    = blockIdx.z;
    const int lane = tid & 63;
    const int h    = (int)blockIdx.y * 8 + (tid >> 6);
    const int w0   = (int)blockIdx.x * 64 + lane;

    const float px = (float)w0 - (float)(IMGW - 1) * 0.5f;
    const float py = (float)(IMGH - 1) * 0.5f - (float)h;

    const float* __restrict__ sino = proj + (size_t)b * NVIEW * NDET;

    float a0 = 0.f, a1 = 0.f, a2 = 0.f, a3 = 0.f;
    float b0 = 0.f, b1 = 0.f, b2 = 0.f, b3 = 0.f;

    Stage s0 = {}, s1 = {};
    fb_load(sino, 0, tid, s0);
    fb_load(sino, 1, tid, s1);
    fb_write(lds[0][0], tid, s0);
    fb_write(lds[0][1], tid, s1);
    fb_load(sino, 2, tid, s0);
    fb_load(sino, 3, tid, s1);
    __syncthreads();

    for (int gg = 0; gg < NGRP; gg += 2) {
        const int buf = (gg >> 1) & 1;
#pragma unroll
        for (int sub = 0; sub < 2; ++sub) {
            const v2h* __restrict__ L = lds[buf][sub];
            const v2f t = cs[gg + sub];
            const v2f m1 = {t.x, -t.y};
            const v2f m2 = {t.y, t.x};
            const v2f pxv = {px, px};
            const v2f pyv = {py, py};
            const v2f gvec = __builtin_elementwise_fma(pxv, m1, pyv * m2);
            const v2f cc = {UCENTER, UCENTER};
            const v2f up = cc + gvec;
            const v2f um = cc - gvec;
            const v2f dd = {128.0f, 128.0f};
            const v2f dm = dd * m1;
            const v2f vp = up + dm;
            const v2f vm = um - dm;

            fb_visit(L, up.x, a0, a1);
            fb_visit(L, um.x, a2, a3);
            fb_visit(L, up.y, a3, a0);
            fb_visit(L, um.y, a1, a2);
            fb_visit(L, vp.x, b0, b1);
            fb_visit(L, vm.x, b2, b3);
            fb_visit(L, vp.y, b3, b0);
            fb_visit(L, vm.y, b1, b2);
        }
        if (gg < NGRP - 2) {
            fb_write(lds[buf ^ 1][0], tid, s0);
            fb_write(lds[buf ^ 1][1], tid, s1);
            if (gg < NGRP - 4) {
                fb_load(sino, gg + 4, tid, s0);
                fb_load(sino, gg + 5, tid, s1);
            }
            __syncthreads();
        }
    }

    float* __restrict__ o = out + (size_t)b * IMGH * IMGW;
    const int hm  = (IMGH - 1) - h;
    const int w1  = w0 + 128;
    const int wm0 = (IMGW - 1) - w0;
    const int wm1 = (IMGW - 1) - w1;
    o[h   * IMGW + w0 ] = a0 * DANG_F;
    o[wm0 * IMGW + h  ] = a1 * DANG_F;
    o[hm  * IMGW + wm0] = a2 * DANG_F;
    o[w0  * IMGW + hm ] = a3 * DANG_F;
    o[h   * IMGW + w1 ] = b0 * DANG_F;
    o[wm1 * IMGW + h  ] = b1 * DANG_F;
    o[hm  * IMGW + wm1] = b2 * DANG_F;
    o[w1  * IMGW + hm ] = b3 * DANG_F;
}

extern "C" void kernel_launch(void* const* d_in, const int* in_sizes, int n_in,
                              void* d_out, int out_size, void* d_ws, size_t ws_size,
                              hipStream_t stream) {
    const float* proj = (const float*)d_in[0];
    float* out = (float*)d_out;

    if (ws_size >= WS_BYTES) {
        E16* ws = (E16*)d_ws;
        prep_kernel<<<dim3(90, BATCH), 192, 0, stream>>>(proj, ws);
        backproject_dma_kernel<<<dim3(2, 32, BATCH), 512, 0, stream>>>(
            (const v8h*)ws, out);
    } else {
        backproject_fb_kernel<<<dim3(2, 32, BATCH), 512, 0, stream>>>(proj, out);
    }
}